// Round 7
// baseline (655.243 us; speedup 1.0000x reference)
//
#include <hip/hip_runtime.h>
#include <math.h>

#define N_NODES 50000
#define N_EDGES 800000
#define F 64
#define R 32
#define C3F 192   // 3*F
#define CAP 48    // bucket capacity; Poisson(16) max row ~45, +8 sigma
#define CSTRIDE 16
#define FILL_BLOCKS ((N_EDGES + 1023) / 1024)   // 4 edges per thread
#define MLP_GRID 1024

#define REP32(X) X(0) X(1) X(2) X(3) X(4) X(5) X(6) X(7) \
                 X(8) X(9) X(10) X(11) X(12) X(13) X(14) X(15) \
                 X(16) X(17) X(18) X(19) X(20) X(21) X(22) X(23) \
                 X(24) X(25) X(26) X(27) X(28) X(29) X(30) X(31)

#define REP64(X) REP32(X) \
                 X(32) X(33) X(34) X(35) X(36) X(37) X(38) X(39) \
                 X(40) X(41) X(42) X(43) X(44) X(45) X(46) X(47) \
                 X(48) X(49) X(50) X(51) X(52) X(53) X(54) X(55) \
                 X(56) X(57) X(58) X(59) X(60) X(61) X(62) X(63)

// ---------------------------------------------------------------------------
// MLP v2: phi = silu(s @ W1 + b1) @ W2 + b2
// Old version was VMEM-INSTRUCTION-bound: 512 vector weight loads per thread
// per node (~340us audit = the stable ~295us residual). New structure
// (gather-proven): 3 waves/block, wave w owns phi segment w. W1 column and
// W2-segment column live in 128 pinned VGPRs loaded ONCE; per node only:
// uniform s_load of the s row (SGPR broadcast FMAs), silu, h broadcast via
// 768B wave-private LDS (uniform ds_read_b128), 64 FMAs, one nt store.
// ---------------------------------------------------------------------------
__global__ __launch_bounds__(192, 2) void mlp_kernel(
    const float* __restrict__ s, const float* __restrict__ W1,
    const float* __restrict__ b1, const float* __restrict__ W2,
    const float* __restrict__ b2, float* __restrict__ phi)
{
    const int lane = threadIdx.x & 63;
    const int w    = threadIdx.x >> 6;      // 0..2 phi segment

    __shared__ float hls[3][64];

    // resident weights: W1[k][lane] and W2[k][w*64+lane], k = 0..63
#define DECL_W(r) float w1_##r, w2_##r;
    REP64(DECL_W)
#undef DECL_W
#define LOAD_W(r) { w1_##r = W1[(r) * F + lane]; \
                    w2_##r = W2[(r) * C3F + w * 64 + lane]; }
    REP64(LOAD_W)
#undef LOAD_W

#define KW1(r) , "+v"(w1_##r)
#define KW2(r) , "+v"(w2_##r)
#define PIN_W \
    asm volatile("" : "+v"(w1_0) KW1(1) KW1(2) KW1(3) KW1(4) KW1(5) KW1(6) KW1(7) KW1(8) KW1(9) KW1(10) KW1(11) KW1(12) KW1(13) KW1(14) KW1(15)); \
    asm volatile("" : "+v"(w1_16) KW1(17) KW1(18) KW1(19) KW1(20) KW1(21) KW1(22) KW1(23) KW1(24) KW1(25) KW1(26) KW1(27) KW1(28) KW1(29) KW1(30) KW1(31)); \
    asm volatile("" : "+v"(w1_32) KW1(33) KW1(34) KW1(35) KW1(36) KW1(37) KW1(38) KW1(39) KW1(40) KW1(41) KW1(42) KW1(43) KW1(44) KW1(45) KW1(46) KW1(47)); \
    asm volatile("" : "+v"(w1_48) KW1(49) KW1(50) KW1(51) KW1(52) KW1(53) KW1(54) KW1(55) KW1(56) KW1(57) KW1(58) KW1(59) KW1(60) KW1(61) KW1(62) KW1(63)); \
    asm volatile("" : "+v"(w2_0) KW2(1) KW2(2) KW2(3) KW2(4) KW2(5) KW2(6) KW2(7) KW2(8) KW2(9) KW2(10) KW2(11) KW2(12) KW2(13) KW2(14) KW2(15)); \
    asm volatile("" : "+v"(w2_16) KW2(17) KW2(18) KW2(19) KW2(20) KW2(21) KW2(22) KW2(23) KW2(24) KW2(25) KW2(26) KW2(27) KW2(28) KW2(29) KW2(30) KW2(31)); \
    asm volatile("" : "+v"(w2_32) KW2(33) KW2(34) KW2(35) KW2(36) KW2(37) KW2(38) KW2(39) KW2(40) KW2(41) KW2(42) KW2(43) KW2(44) KW2(45) KW2(46) KW2(47)); \
    asm volatile("" : "+v"(w2_48) KW2(49) KW2(50) KW2(51) KW2(52) KW2(53) KW2(54) KW2(55) KW2(56) KW2(57) KW2(58) KW2(59) KW2(60) KW2(61) KW2(62) KW2(63));
    PIN_W

    const float b1l = b1[lane];
    const float b2l = b2[w * 64 + lane];

    for (int node = blockIdx.x; node < N_NODES; node += gridDim.x) {
        PIN_W   // keep weights in true VGPRs across iterations

        const float4* sp4 = (const float4*)(s + (size_t)node * F);  // uniform

        // hidden: h[lane] = silu(b1 + sum_k s[k]*W1[k][lane])
        float hh0 = b1l, hh1 = 0.f, hh2 = 0.f, hh3 = 0.f;
#define HF4(q, r0, r1, r2, r3) { float4 sq = sp4[q]; \
        hh0 += sq.x * w1_##r0; hh1 += sq.y * w1_##r1; \
        hh2 += sq.z * w1_##r2; hh3 += sq.w * w1_##r3; }
        HF4(0, 0, 1, 2, 3)     HF4(1, 4, 5, 6, 7)
        HF4(2, 8, 9, 10, 11)   HF4(3, 12, 13, 14, 15)
        HF4(4, 16, 17, 18, 19) HF4(5, 20, 21, 22, 23)
        HF4(6, 24, 25, 26, 27) HF4(7, 28, 29, 30, 31)
        HF4(8, 32, 33, 34, 35) HF4(9, 36, 37, 38, 39)
        HF4(10, 40, 41, 42, 43) HF4(11, 44, 45, 46, 47)
        HF4(12, 48, 49, 50, 51) HF4(13, 52, 53, 54, 55)
        HF4(14, 56, 57, 58, 59) HF4(15, 60, 61, 62, 63)
#undef HF4
        float a = (hh0 + hh1) + (hh2 + hh3);
        float hval = a / (1.f + __expf(-a));     // silu
        hls[w][lane] = hval;

        // phi segment: p = b2 + sum_k h[k]*W2[k][w*64+lane]
        // h broadcast through wave-private LDS (uniform ds_read_b128)
        float p0 = b2l, p1 = 0.f, p2 = 0.f, p3 = 0.f;
        const float4* hp = (const float4*)&hls[w][0];
#define PF4(q, r0, r1, r2, r3) { float4 hq = hp[q]; \
        p0 += hq.x * w2_##r0; p1 += hq.y * w2_##r1; \
        p2 += hq.z * w2_##r2; p3 += hq.w * w2_##r3; }
        PF4(0, 0, 1, 2, 3)     PF4(1, 4, 5, 6, 7)
        PF4(2, 8, 9, 10, 11)   PF4(3, 12, 13, 14, 15)
        PF4(4, 16, 17, 18, 19) PF4(5, 20, 21, 22, 23)
        PF4(6, 24, 25, 26, 27) PF4(7, 28, 29, 30, 31)
        PF4(8, 32, 33, 34, 35) PF4(9, 36, 37, 38, 39)
        PF4(10, 40, 41, 42, 43) PF4(11, 44, 45, 46, 47)
        PF4(12, 48, 49, 50, 51) PF4(13, 52, 53, 54, 55)
        PF4(14, 56, 57, 58, 59) PF4(15, 60, 61, 62, 63)
#undef PF4
        float pv = (p0 + p1) + (p2 + p3);
        __builtin_nontemporal_store(pv, &phi[(size_t)node * C3F + w * 64 + lane]);
    }
#undef KW1
#undef KW2
#undef PIN_W
}

// ---------------------------------------------------------------------------
// Fill kernel: bucket[i][pos] = (e, j). 4 edges/thread. Standalone so its
// counters surface in top-5 if it is the residual beast.
// ---------------------------------------------------------------------------
__global__ __launch_bounds__(256) void fill_kernel(
    const int* __restrict__ eidx, int* __restrict__ counts,
    int2* __restrict__ bucket)
{
    int base = blockIdx.x * 1024 + threadIdx.x;
    int ii[4], jj[4];
#pragma unroll
    for (int q = 0; q < 4; q++) {
        int e = base + q * 256;
        ii[q] = -1;
        if (e < N_EDGES) {
            ii[q] = __builtin_nontemporal_load(&eidx[e]);
            jj[q] = __builtin_nontemporal_load(&eidx[N_EDGES + e]);
        }
    }
#pragma unroll
    for (int q = 0; q < 4; q++) {
        int e = base + q * 256;
        if (ii[q] >= 0) {
            int pos = atomicAdd(&counts[ii[q] * CSTRIDE], 1);
            if (pos < CAP)
                bucket[(size_t)ii[q] * CAP + pos] = make_int2(e, jj[q]);
        }
    }
}

// ---------------------------------------------------------------------------
// Gather: v3 verbatim (best measured: 277us, VALU 70%) — depth-1 rotating
// pipeline, compiler-scheduled uniform radial loads, 96 Wr pinned. Launched
// as TWO half-grids so each dispatch ~140us < fill/mlp if those are the
// residual -> they surface in next round's top-5.
// ---------------------------------------------------------------------------
__global__ __launch_bounds__(64, 4) void gather_kernel(
    const float* __restrict__ s, const float* __restrict__ v,
    const float* __restrict__ phi, const float* __restrict__ radial,
    const float* __restrict__ f_cut, const float* __restrict__ unit_vec,
    const float* __restrict__ Wr, const float* __restrict__ br,
    const int* __restrict__ counts, const int2* __restrict__ bucket,
    float* __restrict__ out_s, float* __restrict__ out_v, int node_base)
{
    const int lane = threadIdx.x;      // 0..63
    const int node = node_base + blockIdx.x;

    // 96 named Wr column values -> forced VGPR residency
#define DECL_WR(r) float wrs##r, wrv##r, wrq##r;
    REP32(DECL_WR)
#undef DECL_WR
#define LOAD_WR(r) { const float* w_ = Wr + (r) * C3F; \
                     wrs##r = w_[lane]; wrv##r = w_[64 + lane]; \
                     wrq##r = w_[128 + lane]; }
    REP32(LOAD_WR)
#undef LOAD_WR
#define KA3(r) , "+v"(wrs##r), "+v"(wrv##r), "+v"(wrq##r)
    asm volatile("" : "+v"(wrs0) KA3(1) KA3(2) KA3(3) KA3(4) KA3(5) KA3(6) KA3(7), "+v"(wrv0), "+v"(wrq0));
    asm volatile("" : "+v"(wrs8) KA3(9) KA3(10) KA3(11) KA3(12) KA3(13) KA3(14) KA3(15), "+v"(wrv8), "+v"(wrq8));
    asm volatile("" : "+v"(wrs16) KA3(17) KA3(18) KA3(19) KA3(20) KA3(21) KA3(22) KA3(23), "+v"(wrv16), "+v"(wrq16));
    asm volatile("" : "+v"(wrs24) KA3(25) KA3(26) KA3(27) KA3(28) KA3(29) KA3(30) KA3(31), "+v"(wrv24), "+v"(wrq24));
#undef KA3

    const float b_s = br[lane], b_vv = br[64 + lane], b_vs = br[128 + lane];

    float acc_s = 0.f, acc_v0 = 0.f, acc_v1 = 0.f, acc_v2 = 0.f;

    int cnt = __builtin_amdgcn_readfirstlane(counts[node * CSTRIDE]);
    cnt = cnt < CAP ? cnt : CAP;
    const int2* row = bucket + (size_t)node * CAP;

    if (cnt > 0) {
        // ---- prologue: full state for edge 0 ----
        int2 ej0 = row[0];
        int e = __builtin_amdgcn_readfirstlane(ej0.x);
        int j = __builtin_amdgcn_readfirstlane(ej0.y);

        const float* pj = phi + (size_t)j * C3F;
        const float* vj = v + (size_t)j * C3F;
        float ps = pj[lane], pvv = pj[64 + lane], pvs = pj[128 + lane];
        float va = vj[lane], vb = vj[64 + lane], vc = vj[128 + lane];

        float fc = f_cut[e];                    // uniform -> SGPR
        float u0 = unit_vec[e * 3 + 0];
        float u1 = unit_vec[e * 3 + 1];
        float u2 = unit_vec[e * 3 + 2];
#define DECL_CR(r) float cr##r;
        REP32(DECL_CR)
#undef DECL_CR
        {
            const float* rp = radial + (size_t)e * R;   // uniform -> s_load
#define LOAD_CR(r) cr##r = rp[r];
            REP32(LOAD_CR)
#undef LOAD_CR
        }

        for (int k = 0; k < cnt; ++k) {
            // ---- prefetch edge k+1: issued here, consumed next iteration ---
            int e_n = e, j_n = j;
            if (k + 1 < cnt) {
                int2 ejn = row[k + 1];
                e_n = __builtin_amdgcn_readfirstlane(ejn.x);
                j_n = __builtin_amdgcn_readfirstlane(ejn.y);
            }
            const float* pn = phi + (size_t)j_n * C3F;
            const float* vn = v + (size_t)j_n * C3F;
            float nps = pn[lane], npvv = pn[64 + lane], npvs = pn[128 + lane];
            float nva = vn[lane], nvb = vn[64 + lane], nvc = vn[128 + lane];
            float fc_n = f_cut[e_n];
            float nu0 = unit_vec[e_n * 3 + 0];
            float nu1 = unit_vec[e_n * 3 + 1];
            float nu2 = unit_vec[e_n * 3 + 2];
#define DECL_NR(r) float nr##r;
            REP32(DECL_NR)
#undef DECL_NR
            {
                const float* rpn = radial + (size_t)e_n * R;
#define LOAD_NR(r) nr##r = rpn[r];
                REP32(LOAD_NR)
#undef LOAD_NR
            }

            // ---- compute edge k: W = radial @ Wr + br (3 indep FMA chains) -
            float ws = b_s, wvv = b_vv, wvs = b_vs;
#define FMA_WR(r) { ws  += cr##r * wrs##r; \
                    wvv += cr##r * wrv##r; \
                    wvs += cr##r * wrq##r; }
            REP32(FMA_WR)
#undef FMA_WR

            float xs  = ps  * ws  * fc;
            float xvv = pvv * wvv * fc;
            float xvs = pvs * wvs * fc;
            acc_s  += xs;
            acc_v0 += va * xvv + xvs * u0;
            acc_v1 += vb * xvv + xvs * u1;
            acc_v2 += vc * xvv + xvs * u2;

            // ---- rotate pipeline ----
            e = e_n; j = j_n;
            ps = nps; pvv = npvv; pvs = npvs;
            va = nva; vb = nvb; vc = nvc;
            fc = fc_n; u0 = nu0; u1 = nu1; u2 = nu2;
#define ROT_R(r) cr##r = nr##r;
            REP32(ROT_R)
#undef ROT_R
        }
    }

    out_s[(size_t)node * F + lane] = s[(size_t)node * F + lane] + acc_s;
    const float* vi = v + (size_t)node * C3F;
    float* ovi = out_v + (size_t)node * C3F;
    ovi[lane]       = vi[lane]       + acc_v0;
    ovi[64 + lane]  = vi[64 + lane]  + acc_v1;
    ovi[128 + lane] = vi[128 + lane] + acc_v2;
}

// ---------------------------------------------------------------------------
extern "C" void kernel_launch(void* const* d_in, const int* in_sizes, int n_in,
                              void* d_out, int out_size, void* d_ws, size_t ws_size,
                              hipStream_t stream)
{
    const float* s      = (const float*)d_in[0];
    const float* v      = (const float*)d_in[1];
    const float* radial = (const float*)d_in[2];
    const float* f_cut  = (const float*)d_in[3];
    const float* unit   = (const float*)d_in[4];
    const int*   eidx   = (const int*)  d_in[5];
    const float* W1     = (const float*)d_in[6];
    const float* b1     = (const float*)d_in[7];
    const float* W2     = (const float*)d_in[8];
    const float* b2     = (const float*)d_in[9];
    const float* Wr     = (const float*)d_in[10];
    const float* br     = (const float*)d_in[11];

    float* out   = (float*)d_out;
    float* out_s = out;
    float* out_v = out + (size_t)N_NODES * F;

    // workspace layout (~61 MB)
    float* phi    = (float*)d_ws;                                  // 50000*192 f32
    int*   counts = (int*)(phi + (size_t)N_NODES * C3F);           // 50000*16 (padded)
    int2*  bucket = (int2*)(counts + (size_t)N_NODES * CSTRIDE);   // 50000*48 int2

    hipMemsetAsync(counts, 0, (size_t)N_NODES * CSTRIDE * sizeof(int), stream);

    fill_kernel<<<FILL_BLOCKS, 256, 0, stream>>>(eidx, counts, bucket);

    mlp_kernel<<<MLP_GRID, 192, 0, stream>>>(s, W1, b1, W2, b2, phi);

    gather_kernel<<<N_NODES / 2, 64, 0, stream>>>(
        s, v, phi, radial, f_cut, unit, Wr, br,
        counts, bucket, out_s, out_v, 0);
    gather_kernel<<<N_NODES / 2, 64, 0, stream>>>(
        s, v, phi, radial, f_cut, unit, Wr, br,
        counts, bucket, out_s, out_v, N_NODES / 2);
}

// Round 8
// 624.931 us; speedup vs baseline: 1.0485x; 1.0485x over previous
//
#include <hip/hip_runtime.h>
#include <math.h>

#define N_NODES 50000
#define N_EDGES 800000
#define F 64
#define R 32
#define C3F 192   // 3*F
#define CAP 48    // bucket capacity; Poisson(16) max row ~45, +8 sigma
#define CSTRIDE 16
#define MLP_BLOCKS ((N_NODES + 31) / 32)
#define FILL_BLOCKS ((N_EDGES + 1023) / 1024)   // 4 edges per thread

#define REP32(X) X(0) X(1) X(2) X(3) X(4) X(5) X(6) X(7) \
                 X(8) X(9) X(10) X(11) X(12) X(13) X(14) X(15) \
                 X(16) X(17) X(18) X(19) X(20) X(21) X(22) X(23) \
                 X(24) X(25) X(26) X(27) X(28) X(29) X(30) X(31)

// ---------------------------------------------------------------------------
// MLP v0 structure (standalone): phi = silu(s @ W1 + b1) @ W2 + b2
// 32 nodes/block, 256 threads, thread=(node,seg). Weights stream from L1/L2
// (broadcast across blocks), high occupancy, no pins, no asm fences.
// v8's pinned-weight 3-wave version was latency-starved (17% occ, asm fences
// serialized iterations): 166us. This structure audits to ~15-25us.
// ---------------------------------------------------------------------------
__global__ __launch_bounds__(256) void mlp_kernel(
    const float* __restrict__ s, const float* __restrict__ W1,
    const float* __restrict__ b1, const float* __restrict__ W2,
    const float* __restrict__ b2, float* __restrict__ phi)
{
    __shared__ float hid_s[32][68];

    int n = threadIdx.x >> 3;          // 0..31 local node
    int seg = threadIdx.x & 7;         // 0..7
    int node = blockIdx.x * 32 + n;
    bool live = node < N_NODES;

    if (live) {
        float sv[F];
        const float4* srow = (const float4*)(s + (size_t)node * F);
#pragma unroll
        for (int q = 0; q < F / 4; q++) {
            float4 t = srow[q];
            sv[4*q+0] = t.x; sv[4*q+1] = t.y; sv[4*q+2] = t.z; sv[4*q+3] = t.w;
        }
        float acc[8];
#pragma unroll
        for (int q = 0; q < 8; q++) acc[q] = b1[seg * 8 + q];
#pragma unroll
        for (int k = 0; k < F; k++) {
            float sk = sv[k];
            const float4* w = (const float4*)(W1 + (size_t)k * F + seg * 8);
            float4 w0 = w[0], w1 = w[1];
            acc[0] += sk * w0.x; acc[1] += sk * w0.y;
            acc[2] += sk * w0.z; acc[3] += sk * w0.w;
            acc[4] += sk * w1.x; acc[5] += sk * w1.y;
            acc[6] += sk * w1.z; acc[7] += sk * w1.w;
        }
#pragma unroll
        for (int q = 0; q < 8; q++) {
            float a = acc[q];
            hid_s[n][seg * 8 + q] = a / (1.f + __expf(-a));   // silu
        }
    }
    __syncthreads();

    if (!live) return;

    float hv[F];
#pragma unroll
    for (int q = 0; q < F; q++) hv[q] = hid_s[n][q];

    float acc[24];
#pragma unroll
    for (int q = 0; q < 24; q++) acc[q] = b2[seg * 24 + q];
#pragma unroll
    for (int k = 0; k < F; k++) {
        float hk = hv[k];
        const float4* w = (const float4*)(W2 + (size_t)k * C3F + seg * 24);
#pragma unroll
        for (int q4 = 0; q4 < 6; q4++) {
            float4 wv = w[q4];
            acc[q4*4+0] += hk * wv.x;
            acc[q4*4+1] += hk * wv.y;
            acc[q4*4+2] += hk * wv.z;
            acc[q4*4+3] += hk * wv.w;
        }
    }
    float4* o = (float4*)(phi + (size_t)node * C3F + seg * 24);
#pragma unroll
    for (int q4 = 0; q4 < 6; q4++)
        o[q4] = make_float4(acc[q4*4+0], acc[q4*4+1], acc[q4*4+2], acc[q4*4+3]);
}

// ---------------------------------------------------------------------------
// Fill kernel: bucket[i][pos] = (e, j). 4 edges/thread, standalone (so its
// counters surface in top-5 if it exceeds a gather half ~140us).
// ---------------------------------------------------------------------------
__global__ __launch_bounds__(256) void fill_kernel(
    const int* __restrict__ eidx, int* __restrict__ counts,
    int2* __restrict__ bucket)
{
    int base = blockIdx.x * 1024 + threadIdx.x;
    int ii[4], jj[4];
#pragma unroll
    for (int q = 0; q < 4; q++) {
        int e = base + q * 256;
        ii[q] = -1;
        if (e < N_EDGES) {
            ii[q] = __builtin_nontemporal_load(&eidx[e]);
            jj[q] = __builtin_nontemporal_load(&eidx[N_EDGES + e]);
        }
    }
#pragma unroll
    for (int q = 0; q < 4; q++) {
        int e = base + q * 256;
        if (ii[q] >= 0) {
            int pos = atomicAdd(&counts[ii[q] * CSTRIDE], 1);
            if (pos < CAP)
                bucket[(size_t)ii[q] * CAP + pos] = make_int2(e, jj[q]);
        }
    }
}

// ---------------------------------------------------------------------------
// Gather: v3 verbatim (best measured: 277us total) — depth-1 rotating
// pipeline, compiler-scheduled uniform radial loads, 96 Wr pinned in VGPRs.
// Two half-grid launches (~140us each) keep the dispatch below fill/mlp if
// those regress, so they surface in top-5.
// ---------------------------------------------------------------------------
__global__ __launch_bounds__(64, 4) void gather_kernel(
    const float* __restrict__ s, const float* __restrict__ v,
    const float* __restrict__ phi, const float* __restrict__ radial,
    const float* __restrict__ f_cut, const float* __restrict__ unit_vec,
    const float* __restrict__ Wr, const float* __restrict__ br,
    const int* __restrict__ counts, const int2* __restrict__ bucket,
    float* __restrict__ out_s, float* __restrict__ out_v, int node_base)
{
    const int lane = threadIdx.x;      // 0..63
    const int node = node_base + blockIdx.x;

    // 96 named Wr column values -> forced VGPR residency
#define DECL_WR(r) float wrs##r, wrv##r, wrq##r;
    REP32(DECL_WR)
#undef DECL_WR
#define LOAD_WR(r) { const float* w_ = Wr + (r) * C3F; \
                     wrs##r = w_[lane]; wrv##r = w_[64 + lane]; \
                     wrq##r = w_[128 + lane]; }
    REP32(LOAD_WR)
#undef LOAD_WR
#define KA3(r) , "+v"(wrs##r), "+v"(wrv##r), "+v"(wrq##r)
    asm volatile("" : "+v"(wrs0) KA3(1) KA3(2) KA3(3) KA3(4) KA3(5) KA3(6) KA3(7), "+v"(wrv0), "+v"(wrq0));
    asm volatile("" : "+v"(wrs8) KA3(9) KA3(10) KA3(11) KA3(12) KA3(13) KA3(14) KA3(15), "+v"(wrv8), "+v"(wrq8));
    asm volatile("" : "+v"(wrs16) KA3(17) KA3(18) KA3(19) KA3(20) KA3(21) KA3(22) KA3(23), "+v"(wrv16), "+v"(wrq16));
    asm volatile("" : "+v"(wrs24) KA3(25) KA3(26) KA3(27) KA3(28) KA3(29) KA3(30) KA3(31), "+v"(wrv24), "+v"(wrq24));
#undef KA3

    const float b_s = br[lane], b_vv = br[64 + lane], b_vs = br[128 + lane];

    float acc_s = 0.f, acc_v0 = 0.f, acc_v1 = 0.f, acc_v2 = 0.f;

    int cnt = __builtin_amdgcn_readfirstlane(counts[node * CSTRIDE]);
    cnt = cnt < CAP ? cnt : CAP;
    const int2* row = bucket + (size_t)node * CAP;

    if (cnt > 0) {
        // ---- prologue: full state for edge 0 ----
        int2 ej0 = row[0];
        int e = __builtin_amdgcn_readfirstlane(ej0.x);
        int j = __builtin_amdgcn_readfirstlane(ej0.y);

        const float* pj = phi + (size_t)j * C3F;
        const float* vj = v + (size_t)j * C3F;
        float ps = pj[lane], pvv = pj[64 + lane], pvs = pj[128 + lane];
        float va = vj[lane], vb = vj[64 + lane], vc = vj[128 + lane];

        float fc = f_cut[e];                    // uniform -> SGPR
        float u0 = unit_vec[e * 3 + 0];
        float u1 = unit_vec[e * 3 + 1];
        float u2 = unit_vec[e * 3 + 2];
#define DECL_CR(r) float cr##r;
        REP32(DECL_CR)
#undef DECL_CR
        {
            const float* rp = radial + (size_t)e * R;   // uniform -> s_load
#define LOAD_CR(r) cr##r = rp[r];
            REP32(LOAD_CR)
#undef LOAD_CR
        }

        for (int k = 0; k < cnt; ++k) {
            // ---- prefetch edge k+1: issued here, consumed next iteration ---
            int e_n = e, j_n = j;
            if (k + 1 < cnt) {
                int2 ejn = row[k + 1];
                e_n = __builtin_amdgcn_readfirstlane(ejn.x);
                j_n = __builtin_amdgcn_readfirstlane(ejn.y);
            }
            const float* pn = phi + (size_t)j_n * C3F;
            const float* vn = v + (size_t)j_n * C3F;
            float nps = pn[lane], npvv = pn[64 + lane], npvs = pn[128 + lane];
            float nva = vn[lane], nvb = vn[64 + lane], nvc = vn[128 + lane];
            float fc_n = f_cut[e_n];
            float nu0 = unit_vec[e_n * 3 + 0];
            float nu1 = unit_vec[e_n * 3 + 1];
            float nu2 = unit_vec[e_n * 3 + 2];
#define DECL_NR(r) float nr##r;
            REP32(DECL_NR)
#undef DECL_NR
            {
                const float* rpn = radial + (size_t)e_n * R;
#define LOAD_NR(r) nr##r = rpn[r];
                REP32(LOAD_NR)
#undef LOAD_NR
            }

            // ---- compute edge k: W = radial @ Wr + br (3 indep FMA chains) -
            float ws = b_s, wvv = b_vv, wvs = b_vs;
#define FMA_WR(r) { ws  += cr##r * wrs##r; \
                    wvv += cr##r * wrv##r; \
                    wvs += cr##r * wrq##r; }
            REP32(FMA_WR)
#undef FMA_WR

            float xs  = ps  * ws  * fc;
            float xvv = pvv * wvv * fc;
            float xvs = pvs * wvs * fc;
            acc_s  += xs;
            acc_v0 += va * xvv + xvs * u0;
            acc_v1 += vb * xvv + xvs * u1;
            acc_v2 += vc * xvv + xvs * u2;

            // ---- rotate pipeline ----
            e = e_n; j = j_n;
            ps = nps; pvv = npvv; pvs = npvs;
            va = nva; vb = nvb; vc = nvc;
            fc = fc_n; u0 = nu0; u1 = nu1; u2 = nu2;
#define ROT_R(r) cr##r = nr##r;
            REP32(ROT_R)
#undef ROT_R
        }
    }

    out_s[(size_t)node * F + lane] = s[(size_t)node * F + lane] + acc_s;
    const float* vi = v + (size_t)node * C3F;
    float* ovi = out_v + (size_t)node * C3F;
    ovi[lane]       = vi[lane]       + acc_v0;
    ovi[64 + lane]  = vi[64 + lane]  + acc_v1;
    ovi[128 + lane] = vi[128 + lane] + acc_v2;
}

// ---------------------------------------------------------------------------
extern "C" void kernel_launch(void* const* d_in, const int* in_sizes, int n_in,
                              void* d_out, int out_size, void* d_ws, size_t ws_size,
                              hipStream_t stream)
{
    const float* s      = (const float*)d_in[0];
    const float* v      = (const float*)d_in[1];
    const float* radial = (const float*)d_in[2];
    const float* f_cut  = (const float*)d_in[3];
    const float* unit   = (const float*)d_in[4];
    const int*   eidx   = (const int*)  d_in[5];
    const float* W1     = (const float*)d_in[6];
    const float* b1     = (const float*)d_in[7];
    const float* W2     = (const float*)d_in[8];
    const float* b2     = (const float*)d_in[9];
    const float* Wr     = (const float*)d_in[10];
    const float* br     = (const float*)d_in[11];

    float* out   = (float*)d_out;
    float* out_s = out;
    float* out_v = out + (size_t)N_NODES * F;

    // workspace layout (~61 MB)
    float* phi    = (float*)d_ws;                                  // 50000*192 f32
    int*   counts = (int*)(phi + (size_t)N_NODES * C3F);           // 50000*16 (padded)
    int2*  bucket = (int2*)(counts + (size_t)N_NODES * CSTRIDE);   // 50000*48 int2

    hipMemsetAsync(counts, 0, (size_t)N_NODES * CSTRIDE * sizeof(int), stream);

    fill_kernel<<<FILL_BLOCKS, 256, 0, stream>>>(eidx, counts, bucket);

    mlp_kernel<<<MLP_BLOCKS, 256, 0, stream>>>(s, W1, b1, W2, b2, phi);

    gather_kernel<<<N_NODES / 2, 64, 0, stream>>>(
        s, v, phi, radial, f_cut, unit, Wr, br,
        counts, bucket, out_s, out_v, 0);
    gather_kernel<<<N_NODES / 2, 64, 0, stream>>>(
        s, v, phi, radial, f_cut, unit, Wr, br,
        counts, bucket, out_s, out_v, N_NODES / 2);
}